// Round 9
// baseline (5406.340 us; speedup 1.0000x reference)
//
#include <hip/hip_runtime.h>
#include <math.h>

#define B_ 32
#define T_ 48
#define ENC_ 1024
#define PRED_ 320
#define JH_ 512
#define NJ_ 1344
#define VOCAB_ 29
#define BLANK_ 28
#define MAXSYM_ 6
#define NSTEPS_ 288
#define BDEC 512
#define GRID_DEC 160
#define NG 8        // independent groups
#define GBAT 4      // batches per group
#define NBLK 20     // blocks per group
#define JPB 16      // LSTM h-cols per block (320/20)
#define NJB 16      // joint blocks per group
#define VPB 32      // joint v-cols per joint block
#define HPAD 324    // padded h row

// ---- workspace layout (float indices) ----
// Stamped (value,step) 8B pairs, publisher-major.
#define FPRE_OFF 0                // 786432
#define WE_OFF   786432           // 28*1280 = 35840
#define H1C2_OFF 822272           // + grp*2560 : 20 blk x 64 pairs
#define PL2_OFF  842752           // + grp*8192 + par*4096 : 16 blk x 128 pairs
#define P0C2_OFF 908288           // + grp*10240 : 20 blk x 256 pairs (full P0 candidate)
#define INT_OFF  990208           // tagD only: grp*320 + lb*16
#define NTAGS    2560
#define STAMPF   167936           // floats to zero from H1C2_OFF

__device__ __forceinline__ float sigm(float v) { return 1.0f / (1.0f + expf(-v)); }

__device__ __forceinline__ int  ld_i(const int* p)   { return __hip_atomic_load((int*)p, __ATOMIC_RELAXED, __HIP_MEMORY_SCOPE_AGENT); }
__device__ __forceinline__ void st_i(int* p, int v)  { __hip_atomic_store(p, v, __ATOMIC_RELAXED, __HIP_MEMORY_SCOPE_AGENT); }

// single-instruction 8B publish: (value, stamp) — self-validating, MALL-visible
__device__ __forceinline__ void st_pair(float* p, float v, int stamp) {
    float2 x; x.x = v; x.y = __int_as_float(stamp);
    asm volatile("global_store_dwordx2 %0, %1, off sc0 sc1" :: "v"(p), "v"(x) : "memory");
}
// fused coherent loads (MALL-served), wait folded in
__device__ __forceinline__ void ldc4_2(const float* p0, const float* p1,
                                       float4& r0, float4& r1) {
    asm volatile("global_load_dwordx4 %0, %2, off sc0 sc1\n\t"
                 "global_load_dwordx4 %1, %3, off sc0 sc1\n\t"
                 "s_waitcnt vmcnt(0)"
                 : "=&v"(r0), "=&v"(r1)
                 : "v"(p0), "v"(p1)
                 : "memory");
}
__device__ __forceinline__ void ldc4_5(const float* p0, const float* p1, const float* p2,
                                       const float* p3, const float* p4,
                                       float4& r0, float4& r1, float4& r2, float4& r3, float4& r4) {
    asm volatile("global_load_dwordx4 %0, %5, off sc0 sc1\n\t"
                 "global_load_dwordx4 %1, %6, off sc0 sc1\n\t"
                 "global_load_dwordx4 %2, %7, off sc0 sc1\n\t"
                 "global_load_dwordx4 %3, %8, off sc0 sc1\n\t"
                 "global_load_dwordx4 %4, %9, off sc0 sc1\n\t"
                 "s_waitcnt vmcnt(0)"
                 : "=&v"(r0), "=&v"(r1), "=&v"(r2), "=&v"(r3), "=&v"(r4)
                 : "v"(p0), "v"(p1), "v"(p2), "v"(p3), "v"(p4)
                 : "memory");
}

#define PIDX(g, ks, jl, gb) ((((g)*8 + (ks))*16 + (jl))*4 + (gb))

// ---------------- init ----------------
__global__ void k_init(float* __restrict__ ws, int* __restrict__ out) {
    int idx = blockIdx.x * blockDim.x + threadIdx.x;
    int stride = gridDim.x * blockDim.x;
    for (int i = idx; i < STAMPF; i += stride) ws[H1C2_OFF + i] = 0.0f;  // stamps=0
    int* wi = (int*)ws;
    for (int i = idx; i < NTAGS; i += stride) wi[INT_OFF + i] = 0;
    for (int i = idx; i < B_*NSTEPS_; i += stride) out[i] = -1;  // lt
    if (idx < B_) out[B_*NSTEPS_ + idx] = 0;                     // lc
}

// ---------------- WE = emb @ Wi0^T  (28 x 1280) ----------------
__global__ __launch_bounds__(256) void k_we(const float* __restrict__ emb,
                                            const float* __restrict__ Wi0,
                                            float* __restrict__ ws) {
    __shared__ float es[PRED_];
    int l = blockIdx.x / 5;
    int rq = blockIdx.x % 5;
    int t = threadIdx.x;
    if (t < PRED_) es[t] = emb[l*PRED_ + t];
    if (t + 256 < PRED_) es[t + 256] = emb[l*PRED_ + t + 256];
    __syncthreads();
    int r = rq*256 + t;
    const float4* wr = (const float4*)(Wi0 + (size_t)r*PRED_);
    float acc = 0.0f;
    #pragma unroll 4
    for (int k4 = 0; k4 < PRED_/4; ++k4) {
        float4 w = wr[k4];
        acc += w.x*es[4*k4] + w.y*es[4*k4+1] + w.z*es[4*k4+2] + w.w*es[4*k4+3];
    }
    ws[WE_OFF + l*(4*PRED_) + r] = acc;
}

// ---------------- Fpre[b][t][j] = x[b,t]·Wj1[j,:1024] + bj1[j] ----------------
__global__ __launch_bounds__(256) void k_fpre(const float* __restrict__ x,
                                              const float* __restrict__ Wj1,
                                              const float* __restrict__ bj1,
                                              float* __restrict__ ws) {
    __shared__ float As[B_][129];
    __shared__ float Bs[64][129];
    int tt = blockIdx.x >> 3;
    int jb = blockIdx.x & 7;
    int tid = threadIdx.x;
    int b = tid >> 3, jq = tid & 7;
    float acc[8] = {0,0,0,0,0,0,0,0};
    for (int kc = 0; kc < ENC_; kc += 128) {
        for (int i = tid; i < B_*128; i += 256) {
            int bb = i >> 7, kk = i & 127;
            As[bb][kk] = x[((size_t)bb*T_ + tt)*ENC_ + kc + kk];
        }
        for (int i = tid; i < 64*128; i += 256) {
            int jj = i >> 7, kk = i & 127;
            Bs[jj][kk] = Wj1[((size_t)(jb*64 + jj))*NJ_ + kc + kk];
        }
        __syncthreads();
        for (int kk = 0; kk < 128; ++kk) {
            float a = As[b][kk];
            #pragma unroll
            for (int u = 0; u < 8; ++u) acc[u] += a * Bs[jq*8 + u][kk];
        }
        __syncthreads();
    }
    #pragma unroll
    for (int u = 0; u < 8; ++u) {
        int j = jb*64 + jq*8 + u;
        ws[FPRE_OFF + ((size_t)b*T_ + tt)*JH_ + j] = acc[u] + bj1[j];
    }
}

// ---------------- persistent decode: 8 independent groups of 20 blocks ----------------
__global__ __launch_bounds__(BDEC) void k_decode(
    const int* __restrict__ out_lens,
    const float* __restrict__ Wh0, const float* __restrict__ b0,
    const float* __restrict__ Wi1, const float* __restrict__ Wh1,
    const float* __restrict__ b1,
    const float* __restrict__ Wj1,
    const float* __restrict__ Wj2, const float* __restrict__ bj2,
    float* __restrict__ ws, int* __restrict__ out)
{
    const int tid = threadIdx.x;
    const int grp = blockIdx.x & 7;        // group
    const int lb  = blockIdx.x >> 3;       // 0..19 group-local
    const int j0  = lb * JPB;              // LSTM col base
    const int v0  = lb * VPB;              // joint col base (lb<16)
    const int bb0 = grp * GBAT;            // global batch base

    float* H1C2g = ws + H1C2_OFF + grp*2560;
    float* PL2g  = ws + PL2_OFF  + grp*8192;
    float* P0C2g = ws + P0C2_OFF + grp*10240;
    const float* WE = ws + WE_OFF;
    const float* FP = ws + FPRE_OFF;
    int* wi = (int*)ws;
    int* tagD = wi + INT_OFF + grp*320;

    // ---- LDS ----
    __shared__ __align__(16) float wi1_s[64*HPAD];   // 83 KB Wi1 slice (64 gate-rows)
    __shared__ __align__(16) float hs0[GBAT*HPAD];   // h0 candidates (full, local)
    __shared__ __align__(16) float hs1[GBAT*HPAD];   // h1 candidates
    __shared__ float parts[2048];
    __shared__ float parts2[2048];                   // P0 scratch
    __shared__ float P0curf[5120];                   // FULL committed P0 [r][g2]
    __shared__ float c0curf[1280], c0candf[1280];    // FULL c0 state [j][g2]
    __shared__ float P1s[256];
    __shared__ float c1cur[64], c1cand[64];
    __shared__ float b0f_s[1280], b1_s[64], bj2_s[32];
    __shared__ float wj2t[VPB*33];                   // [v][l] transposed
    __shared__ float jg_c[VPB*GBAT];                 // [v][g2]
    __shared__ float hid_s[GBAT*33];
    __shared__ float logits_s[GBAT*33];
    __shared__ int ti_l[GBAT], last_l[GBAT], sa_l[GBAT], lc_l[GBAT], olen_s[GBAT];
    __shared__ unsigned s_masks[2];

    // ---- one-time preload ----
    for (int i = tid; i < 64*PRED_; i += BDEC) {
        int r = i / PRED_, c = i % PRED_;
        int g = r >> 4, jj = r & 15;
        wi1_s[r*HPAD + c] = Wi1[((size_t)(g*PRED_ + j0 + jj))*PRED_ + c];
    }
    if (lb < NJB) {
        for (int i = tid; i < VPB*32; i += BDEC) {
            int v = i >> 5, l = i & 31;
            wj2t[v*33 + l] = (l < VOCAB_) ? Wj2[(size_t)l*JH_ + v0 + v] : 0.f;
        }
    }
    for (int i = tid; i < 1280; i += BDEC) {
        b0f_s[i] = b0[i];
        c0curf[i] = 0.f; c0candf[i] = 0.f;
    }
    for (int i = tid; i < 5120; i += BDEC) P0curf[i] = 0.f;
    if (tid < 64) {
        int g = tid >> 4, jj = tid & 15;
        b1_s[tid] = b1[g*PRED_ + j0 + jj];
        c1cur[tid] = 0.f; c1cand[tid] = 0.f;
    }
    if (tid < VOCAB_) bj2_s[tid] = bj2[tid];
    if (tid < GBAT) {
        olen_s[tid] = out_lens[bb0 + tid];
        ti_l[tid] = 0; last_l[tid] = -1; sa_l[tid] = 0; lc_l[tid] = 0;
    }
    for (int i = tid; i < GBAT*HPAD; i += BDEC) { hs0[i] = 0.f; hs1[i] = 0.f; }
    __syncthreads();

    const int gb  = tid & 3;          // batch
    const int jl  = (tid >> 2) & 15;  // col within block
    const int ks  = tid >> 6;         // 0..7 (k-chunks of 40)
    unsigned nbm = 0xfu, actm = 0xfu;
    int last_nb = -1;                 // last step that published P0 candidates

    for (int s = 0; s < NSTEPS_; ++s) {
        const int par = s & 1;
        const int st = s + 1;

        // ===== Fpre prefetch (joint blocks; ti known from prev decide) =====
        float f_reg = 0.f;
        if (lb < NJB && tid < 128) {
            int v_ = tid & 31, g2_ = tid >> 5;
            if ((actm >> g2_) & 1) {
                int tm = min(ti_l[g2_], T_ - 1);
                f_reg = FP[((size_t)(bb0+g2_)*T_ + tm)*JH_ + v0 + v_];
            }
        }

        if (nbm) {
            // ===== top-gather: full P0 candidate (published at last_nb; long-arrived)
            // merge-commit into P0curf for batches accepted at prev decide (nbm).
            if (last_nb >= 0) {
                const int pst = last_nb + 1;
                int p0 = tid * 10;                     // 5120 pairs / 512 threads
                const float* base = P0C2g + p0*2;
                float4 q0, q1, q2, q3, q4;
                for (;;) {
                    ldc4_5(base, base+4, base+8, base+12, base+16, q0, q1, q2, q3, q4);
                    bool ok = __float_as_int(q0.y)==pst && __float_as_int(q0.w)==pst
                           && __float_as_int(q1.y)==pst && __float_as_int(q1.w)==pst
                           && __float_as_int(q2.y)==pst && __float_as_int(q2.w)==pst
                           && __float_as_int(q3.y)==pst && __float_as_int(q3.w)==pst
                           && __float_as_int(q4.y)==pst && __float_as_int(q4.w)==pst;
                    if (ok) break;
                    __builtin_amdgcn_s_sleep(1);
                }
                float vv[10] = {q0.x,q0.z,q1.x,q1.z,q2.x,q2.z,q3.x,q3.z,q4.x,q4.z};
                #pragma unroll
                for (int i = 0; i < 10; ++i) {
                    int p = p0 + i;
                    int g2 = p & 3;
                    if ((nbm >> g2) & 1) {
                        int rl = (p >> 2) & 63, lbs = p >> 8;
                        int r = (rl >> 4)*320 + lbs*16 + (rl & 15);
                        P0curf[r*4 + g2] = vv[i];
                    }
                }
            }
            __syncthreads();

            // ===== S1-full (local: gates0 from P0curf+WE+b0; full h0cand -> hs0) =====
            for (int idx = tid; idx < 1280; idx += BDEC) {
                int g2 = idx & 3, j = idx >> 2;
                if ((nbm >> g2) & 1) {
                    int ls = last_l[g2];
                    float gt[4];
                    #pragma unroll
                    for (int g = 0; g < 4; ++g) {
                        int r = g*320 + j;
                        float v = P0curf[r*4 + g2] + b0f_s[r];
                        if (ls >= 0) v += WE[(size_t)ls*1280 + r];
                        gt[g] = v;
                    }
                    float cn = sigm(gt[1])*c0curf[j*4 + g2] + sigm(gt[0])*tanhf(gt[2]);
                    float hn = sigm(gt[3])*tanhf(cn);
                    c0candf[j*4 + g2] = cn;
                    hs0[g2*HPAD + j] = hn;
                }
            }
            // ===== P1 = Wh1 · h1cur (fused in same phase; hs1 stable) =====
            {
                const float* hr = &hs1[gb*HPAD];
                int k0 = ks * 40;
                float a0=0.f,a1=0.f,a2=0.f,a3=0.f;
                const float* w0 = Wh1 + ((size_t)(0*PRED_ + j0 + jl))*PRED_;
                const float* w1 = Wh1 + ((size_t)(1*PRED_ + j0 + jl))*PRED_;
                const float* w2 = Wh1 + ((size_t)(2*PRED_ + j0 + jl))*PRED_;
                const float* w3 = Wh1 + ((size_t)(3*PRED_ + j0 + jl))*PRED_;
                #pragma unroll 10
                for (int kk = k0; kk < k0 + 40; kk += 4) {
                    float4 h = *(const float4*)&hr[kk];
                    float4 q0 = *(const float4*)(w0 + kk);
                    float4 q1 = *(const float4*)(w1 + kk);
                    float4 q2 = *(const float4*)(w2 + kk);
                    float4 q3 = *(const float4*)(w3 + kk);
                    a0 += q0.x*h.x+q0.y*h.y+q0.z*h.z+q0.w*h.w;
                    a1 += q1.x*h.x+q1.y*h.y+q1.z*h.z+q1.w*h.w;
                    a2 += q2.x*h.x+q2.y*h.y+q2.z*h.z+q2.w*h.w;
                    a3 += q3.x*h.x+q3.y*h.y+q3.z*h.z+q3.w*h.w;
                }
                parts[PIDX(0,ks,jl,gb)] = a0;
                parts[PIDX(1,ks,jl,gb)] = a1;
                parts[PIDX(2,ks,jl,gb)] = a2;
                parts[PIDX(3,ks,jl,gb)] = a3;
            }
            __syncthreads();
            if (tid < 256) {
                int r = tid >> 2, g2 = tid & 3;
                int g = r >> 4, jj = r & 15;
                float v = 0.f;
                #pragma unroll
                for (int k = 0; k < 8; ++k) v += parts[PIDX(g,k,jj,g2)];
                P1s[r*4 + g2] = v;
            }
            __syncthreads();

            // ===== S2: Wi1·h0cand (LDS weights; hs0 fully local now) =====
            {
                const float* hr = &hs0[gb*HPAD];
                int k0 = ks * 40;
                float a0=0.f,a1=0.f,a2=0.f,a3=0.f;
                #pragma unroll 10
                for (int kk = k0; kk < k0 + 40; kk += 4) {
                    float4 h = *(const float4*)&hr[kk];
                    float4 q0 = *(const float4*)&wi1_s[(0*16+jl)*HPAD + kk];
                    float4 q1 = *(const float4*)&wi1_s[(1*16+jl)*HPAD + kk];
                    float4 q2 = *(const float4*)&wi1_s[(2*16+jl)*HPAD + kk];
                    float4 q3 = *(const float4*)&wi1_s[(3*16+jl)*HPAD + kk];
                    a0 += q0.x*h.x+q0.y*h.y+q0.z*h.z+q0.w*h.w;
                    a1 += q1.x*h.x+q1.y*h.y+q1.z*h.z+q1.w*h.w;
                    a2 += q2.x*h.x+q2.y*h.y+q2.z*h.z+q2.w*h.w;
                    a3 += q3.x*h.x+q3.y*h.y+q3.z*h.z+q3.w*h.w;
                }
                parts[PIDX(0,ks,jl,gb)] = a0;
                parts[PIDX(1,ks,jl,gb)] = a1;
                parts[PIDX(2,ks,jl,gb)] = a2;
                parts[PIDX(3,ks,jl,gb)] = a3;
            }
            __syncthreads();
            // gates1 assemble + stamped publish h1cand (self via LDS)
            if (tid < 64) {
                int g2 = tid & 3, jj = tid >> 2;
                if ((nbm >> g2) & 1) {
                    float gt[4];
                    #pragma unroll
                    for (int g = 0; g < 4; ++g) {
                        int r = g*16 + jj;
                        float v = P1s[r*4 + g2] + b1_s[r];
                        #pragma unroll
                        for (int k = 0; k < 8; ++k) v += parts[PIDX(g,k,jj,g2)];
                        gt[g] = v;
                    }
                    float cn = sigm(gt[1])*c1cur[tid] + sigm(gt[0])*tanhf(gt[2]);
                    float hn = sigm(gt[3])*tanhf(cn);
                    c1cand[tid] = cn;
                    hs1[g2*HPAD + j0 + jj] = hn;                 // self short-circuit
                    st_pair(&H1C2g[(lb*64 + tid)*2], hn, st);
                }
            }
            // ===== P0 half1 (gates 0-1) = Wh0·h0cand (cover for h1 flight) =====
            {
                const float* hr = &hs0[gb*HPAD];
                int k0 = ks * 40;
                float a0=0.f,a1=0.f;
                const float* w0 = Wh0 + ((size_t)(0*PRED_ + j0 + jl))*PRED_;
                const float* w1 = Wh0 + ((size_t)(1*PRED_ + j0 + jl))*PRED_;
                #pragma unroll 10
                for (int kk = k0; kk < k0 + 40; kk += 4) {
                    float4 h = *(const float4*)&hr[kk];
                    float4 q0 = *(const float4*)(w0 + kk);
                    float4 q1 = *(const float4*)(w1 + kk);
                    a0 += q0.x*h.x+q0.y*h.y+q0.z*h.z+q0.w*h.w;
                    a1 += q1.x*h.x+q1.y*h.y+q1.z*h.z+q1.w*h.w;
                }
                parts2[PIDX(0,ks,jl,gb)] = a0;
                parts2[PIDX(1,ks,jl,gb)] = a1;
            }
            // ===== hopB: single-RT stamped gather of h1cand =====
            {
                int b = tid >> 4, jj = tid & 15;
                if (tid < 320 && b != lb) {
                    const bool n0=(nbm>>0)&1, n1=(nbm>>1)&1, n2=(nbm>>2)&1, n3=(nbm>>3)&1;
                    const float* a0 = H1C2g + tid*8;
                    const float* a1 = a0 + 4;
                    float4 r0, r1;
                    for (;;) {
                        ldc4_2(a0, a1, r0, r1);
                        bool ok = (!n0 || __float_as_int(r0.y)==st)
                               && (!n1 || __float_as_int(r0.w)==st)
                               && (!n2 || __float_as_int(r1.y)==st)
                               && (!n3 || __float_as_int(r1.w)==st);
                        if (ok) break;
                        __builtin_amdgcn_s_sleep(1);
                    }
                    if (n0) hs1[0*HPAD + b*16 + jj] = r0.x;
                    if (n1) hs1[1*HPAD + b*16 + jj] = r0.z;
                    if (n2) hs1[2*HPAD + b*16 + jj] = r1.x;
                    if (n3) hs1[3*HPAD + b*16 + jj] = r1.z;
                }
            }
            __syncthreads();
        } else {
            // blank step: PL[par] overwrite needs step-(s-2) readers done
            if (lb < NJB) {
                if (tid < NBLK) { while (ld_i(&tagD[tid*16]) < s-1) __builtin_amdgcn_s_sleep(1); }
                __syncthreads();
            }
        }

        // ===== S3a: joint blocks =====
        if (lb < NJB) {
            if (nbm) {
                int v = tid & 31, g2 = (tid >> 5) & 3, ks2 = tid >> 7;
                if ((nbm >> g2) & 1) {
                    const float* hr = &hs1[g2*HPAD];
                    const float* wt = Wj1 + ((size_t)(v0 + v))*NJ_ + ENC_ + ks2*80;
                    const float* hk = hr + ks2*80;
                    float p = 0.f;
                    #pragma unroll 20
                    for (int kk = 0; kk < 80; kk += 4) {
                        float4 w4 = *(const float4*)(wt + kk);
                        float4 h  = *(const float4*)(hk + kk);
                        p += w4.x*h.x + w4.y*h.y + w4.z*h.z + w4.w*h.w;
                    }
                    parts[(v*4 + g2)*4 + ks2] = p;
                }
            }
            __syncthreads();
            if (tid < 128) {
                int v = tid & 31, g2 = tid >> 5;
                if (nbm && ((nbm >> g2) & 1)) {
                    jg_c[v*4 + g2] = parts[(v*4+g2)*4+0] + parts[(v*4+g2)*4+1]
                                   + parts[(v*4+g2)*4+2] + parts[(v*4+g2)*4+3];
                }
                if ((actm >> g2) & 1) {
                    hid_s[g2*33 + v] = fmaxf(f_reg + jg_c[v*4 + g2], 0.f);
                }
            }
            __syncthreads();
            if (tid < 128) {
                int g2 = tid >> 5, l = tid & 31;
                const float* hb = &hid_s[g2*33];
                float acc = 0.f;
                #pragma unroll 8
                for (int v = 0; v < VPB; ++v) acc += wj2t[v*33 + l] * hb[v];
                st_pair(&PL2g[par*4096 + (lb*128 + tid)*2], acc, st);
            }
        }

        // ===== P0 half2 (gates 2-3; cover for PL flight) + reduce + publish =====
        if (nbm) {
            {
                const float* hr = &hs0[gb*HPAD];
                int k0 = ks * 40;
                float a2=0.f,a3=0.f;
                const float* w2 = Wh0 + ((size_t)(2*PRED_ + j0 + jl))*PRED_;
                const float* w3 = Wh0 + ((size_t)(3*PRED_ + j0 + jl))*PRED_;
                #pragma unroll 10
                for (int kk = k0; kk < k0 + 40; kk += 4) {
                    float4 h = *(const float4*)&hr[kk];
                    float4 q2 = *(const float4*)(w2 + kk);
                    float4 q3 = *(const float4*)(w3 + kk);
                    a2 += q2.x*h.x+q2.y*h.y+q2.z*h.z+q2.w*h.w;
                    a3 += q3.x*h.x+q3.y*h.y+q3.z*h.z+q3.w*h.w;
                }
                parts2[PIDX(2,ks,jl,gb)] = a2;
                parts2[PIDX(3,ks,jl,gb)] = a3;
            }
            __syncthreads();
            // reduce + publish this block's 256 P0-candidate pairs (consumed next nb-step top)
            if (tid < 256) {
                int r = tid >> 2, g2 = tid & 3;
                int g = r >> 4, jj = r & 15;
                float v = 0.f;
                #pragma unroll
                for (int k = 0; k < 8; ++k) v += parts2[PIDX(g,k,jj,g2)];
                st_pair(&P0C2g[(lb*256 + tid)*2], v, st);
            }
        }

        // ===== hopC: publisher-isolated stamped gather (thread -> ONE jb, 32B) =====
        {
            int p0 = tid * 4;                              // pairs p0..p0+3, jb = tid>>5
            const float* a0 = PL2g + par*4096 + p0*2;
            float4 r0, r1;
            for (;;) {
                ldc4_2(a0, a0 + 4, r0, r1);
                if (__float_as_int(r0.y)==st && __float_as_int(r0.w)==st &&
                    __float_as_int(r1.y)==st && __float_as_int(r1.w)==st) break;
                __builtin_amdgcn_s_sleep(1);
            }
            parts[p0+0]=r0.x; parts[p0+1]=r0.z; parts[p0+2]=r1.x; parts[p0+3]=r1.z;
        }
        __syncthreads();
        if (tid < 128) {
            float v = 0.f;
            #pragma unroll
            for (int jb = 0; jb < 16; ++jb) v += parts[jb*128 + tid];
            int g2 = tid >> 5, l = tid & 31;
            logits_s[g2*33 + l] = (l < VOCAB_) ? (v + bj2_s[l]) : -1e30f;
        }
        __syncthreads();

        // ===== local redundant decide (one wave + ballot) =====
        if (tid < 64) {
            bool nbb = false, actb = false;
            if (tid < GBAT && ((actm >> tid) & 1)) {
                const int g2 = tid;
                float best = -1e30f; int bi = 0;
                for (int l = 0; l < VOCAB_; ++l) {
                    float v = logits_s[g2*33 + l];
                    if (v > best) { best = v; bi = l; }
                }
                const int blankness = (bi == BLANK_) ? 1 : 0;
                int tiv = ti_l[g2] + blankness;
                if (tiv >= olen_s[g2]) {
                    ti_l[g2] = tiv;                      // frozen
                } else {
                    int notb = 1 - blankness;
                    int sav = blankness ? 0 : sa_l[g2];
                    int nl = last_l[g2];
                    int lcn = lc_l[g2];
                    if (notb) {
                        lcn += 1;
                        if (lb == g2) {                  // designated writer
                            int bglob = bb0 + g2;
                            if (lcn < NSTEPS_) st_i(&out[bglob*NSTEPS_ + lcn], bi);
                            st_i(&out[B_*NSTEPS_ + bglob], lcn);
                        }
                        nl = bi;
                        sav += 1;
                    }
                    if (sav >= MAXSYM_) { tiv += 1; sav = 0; }
                    ti_l[g2] = tiv; sa_l[g2] = sav; last_l[g2] = nl; lc_l[g2] = lcn;
                    nbb = (notb != 0); actb = true;
                }
            }
            unsigned long long bn = __ballot(nbb);
            unsigned long long ba = __ballot(actb);
            if (tid == 0) { s_masks[0] = (unsigned)bn; s_masks[1] = (unsigned)ba; }
        }
        __syncthreads();
        const unsigned nbm_new = s_masks[0];
        actm = s_masks[1];
        // commit accepted candidates (c0 full-replicated; c1 distributed).
        // P0 commit happens via next nb-step's top-gather merge.
        if (tid < 64) {
            if ((nbm_new >> (tid & 3)) & 1) c1cur[tid] = c1cand[tid];
        }
        for (int i = tid; i < 1280; i += BDEC) {
            if ((nbm_new >> (i & 3)) & 1) c0curf[i] = c0candf[i];
        }
        __syncthreads();
        if (nbm) last_nb = s;
        nbm = nbm_new;
        if (tid == 0) st_i(&tagD[lb*16], s + 1);
        if (!actm) break;
    }
}

extern "C" void kernel_launch(void* const* d_in, const int* in_sizes, int n_in,
                              void* d_out, int out_size, void* d_ws, size_t ws_size,
                              hipStream_t stream) {
    const float* x    = (const float*)d_in[0];
    const int*   olen = (const int*)d_in[1];
    const float* emb  = (const float*)d_in[2];
    const float* Wi0  = (const float*)d_in[3];
    const float* Wh0  = (const float*)d_in[4];
    const float* b0   = (const float*)d_in[5];
    const float* Wi1  = (const float*)d_in[6];
    const float* Wh1  = (const float*)d_in[7];
    const float* b1   = (const float*)d_in[8];
    const float* Wj1  = (const float*)d_in[9];
    const float* bj1  = (const float*)d_in[10];
    const float* Wj2  = (const float*)d_in[11];
    const float* bj2  = (const float*)d_in[12];
    float* ws = (float*)d_ws;
    int* out = (int*)d_out;

    hipLaunchKernelGGL(k_init, dim3(256), dim3(256), 0, stream, ws, out);
    hipLaunchKernelGGL(k_we,   dim3(28*5), dim3(256), 0, stream, emb, Wi0, ws);
    hipLaunchKernelGGL(k_fpre, dim3(T_*8), dim3(256), 0, stream, x, Wj1, bj1, ws);
    hipLaunchKernelGGL(k_decode, dim3(GRID_DEC), dim3(BDEC), 0, stream,
                       olen, Wh0, b0, Wi1, Wh1, b1, Wj1, Wj2, bj2, ws, out);
}

// Round 10
// 4139.331 us; speedup vs baseline: 1.3061x; 1.3061x over previous
//
#include <hip/hip_runtime.h>
#include <math.h>

#define B_ 32
#define T_ 48
#define ENC_ 1024
#define PRED_ 320
#define JH_ 512
#define NJ_ 1344
#define VOCAB_ 29
#define BLANK_ 28
#define MAXSYM_ 6
#define NSTEPS_ 288
#define BDEC 512
#define GRID_DEC 160
#define NG 8        // independent groups
#define GBAT 4      // batches per group
#define NBLK 20     // blocks per group
#define JPB 16      // LSTM h-cols per block (320/20)
#define NJB 16      // joint blocks per group
#define VPB 32      // joint v-cols per joint block
#define HPAD 324    // padded h row

// ---- workspace layout (float indices) ----
// Stamped (value,step) 8B pairs, publisher-major.
#define FPRE_OFF 0                // 786432
#define WE_OFF   786432           // 28*1280 = 35840
#define H0C2_OFF 822272           // + grp*2560 : 20 blk x 64 pairs (publisher-major)
#define H1C2_OFF 842752           // + grp*2560
#define PL2_OFF  863232           // + grp*8192 + par*4096 : 16 blk x 128 pairs
#define INT_OFF  928768           // tagD only: grp*320 + lb*16
#define NTAGS    2560
#define STAMPF   106496           // floats to zero from H0C2_OFF

__device__ __forceinline__ float sigm(float v) { return 1.0f / (1.0f + expf(-v)); }

__device__ __forceinline__ int  ld_i(const int* p)   { return __hip_atomic_load((int*)p, __ATOMIC_RELAXED, __HIP_MEMORY_SCOPE_AGENT); }
__device__ __forceinline__ void st_i(int* p, int v)  { __hip_atomic_store(p, v, __ATOMIC_RELAXED, __HIP_MEMORY_SCOPE_AGENT); }

// single-instruction 8B publish: (value, stamp) — self-validating, MALL-visible
__device__ __forceinline__ void st_pair(float* p, float v, int stamp) {
    float2 x; x.x = v; x.y = __int_as_float(stamp);
    asm volatile("global_store_dwordx2 %0, %1, off sc0 sc1" :: "v"(p), "v"(x) : "memory");
}
// fused coherent loads (MALL-served), wait folded in
__device__ __forceinline__ void ldc4_2(const float* p0, const float* p1,
                                       float4& r0, float4& r1) {
    asm volatile("global_load_dwordx4 %0, %2, off sc0 sc1\n\t"
                 "global_load_dwordx4 %1, %3, off sc0 sc1\n\t"
                 "s_waitcnt vmcnt(0)"
                 : "=&v"(r0), "=&v"(r1)
                 : "v"(p0), "v"(p1)
                 : "memory");
}

#define PIDX(g, ks, jl, gb) ((((g)*8 + (ks))*16 + (jl))*4 + (gb))

// ---------------- init ----------------
__global__ void k_init(float* __restrict__ ws, int* __restrict__ out) {
    int idx = blockIdx.x * blockDim.x + threadIdx.x;
    int stride = gridDim.x * blockDim.x;
    for (int i = idx; i < STAMPF; i += stride) ws[H0C2_OFF + i] = 0.0f;  // stamps=0
    int* wi = (int*)ws;
    for (int i = idx; i < NTAGS; i += stride) wi[INT_OFF + i] = 0;
    for (int i = idx; i < B_*NSTEPS_; i += stride) out[i] = -1;  // lt
    if (idx < B_) out[B_*NSTEPS_ + idx] = 0;                     // lc
}

// ---------------- WE = emb @ Wi0^T  (28 x 1280) ----------------
__global__ __launch_bounds__(256) void k_we(const float* __restrict__ emb,
                                            const float* __restrict__ Wi0,
                                            float* __restrict__ ws) {
    __shared__ float es[PRED_];
    int l = blockIdx.x / 5;
    int rq = blockIdx.x % 5;
    int t = threadIdx.x;
    if (t < PRED_) es[t] = emb[l*PRED_ + t];
    if (t + 256 < PRED_) es[t + 256] = emb[l*PRED_ + t + 256];
    __syncthreads();
    int r = rq*256 + t;
    const float4* wr = (const float4*)(Wi0 + (size_t)r*PRED_);
    float acc = 0.0f;
    #pragma unroll 4
    for (int k4 = 0; k4 < PRED_/4; ++k4) {
        float4 w = wr[k4];
        acc += w.x*es[4*k4] + w.y*es[4*k4+1] + w.z*es[4*k4+2] + w.w*es[4*k4+3];
    }
    ws[WE_OFF + l*(4*PRED_) + r] = acc;
}

// ---------------- Fpre[b][t][j] = x[b,t]·Wj1[j,:1024] + bj1[j] ----------------
__global__ __launch_bounds__(256) void k_fpre(const float* __restrict__ x,
                                              const float* __restrict__ Wj1,
                                              const float* __restrict__ bj1,
                                              float* __restrict__ ws) {
    __shared__ float As[B_][129];
    __shared__ float Bs[64][129];
    int tt = blockIdx.x >> 3;
    int jb = blockIdx.x & 7;
    int tid = threadIdx.x;
    int b = tid >> 3, jq = tid & 7;
    float acc[8] = {0,0,0,0,0,0,0,0};
    for (int kc = 0; kc < ENC_; kc += 128) {
        for (int i = tid; i < B_*128; i += 256) {
            int bb = i >> 7, kk = i & 127;
            As[bb][kk] = x[((size_t)bb*T_ + tt)*ENC_ + kc + kk];
        }
        for (int i = tid; i < 64*128; i += 256) {
            int jj = i >> 7, kk = i & 127;
            Bs[jj][kk] = Wj1[((size_t)(jb*64 + jj))*NJ_ + kc + kk];
        }
        __syncthreads();
        for (int kk = 0; kk < 128; ++kk) {
            float a = As[b][kk];
            #pragma unroll
            for (int u = 0; u < 8; ++u) acc[u] += a * Bs[jq*8 + u][kk];
        }
        __syncthreads();
    }
    #pragma unroll
    for (int u = 0; u < 8; ++u) {
        int j = jb*64 + jq*8 + u;
        ws[FPRE_OFF + ((size_t)b*T_ + tt)*JH_ + j] = acc[u] + bj1[j];
    }
}

// ---------------- persistent decode: 8 independent groups of 20 blocks ----------------
__global__ __launch_bounds__(BDEC) void k_decode(
    const int* __restrict__ out_lens,
    const float* __restrict__ Wh0, const float* __restrict__ b0,
    const float* __restrict__ Wi1, const float* __restrict__ Wh1,
    const float* __restrict__ b1,
    const float* __restrict__ Wj1,
    const float* __restrict__ Wj2, const float* __restrict__ bj2,
    float* __restrict__ ws, int* __restrict__ out)
{
    const int tid = threadIdx.x;
    const int grp = blockIdx.x & 7;        // group
    const int lb  = blockIdx.x >> 3;       // 0..19 group-local
    const int j0  = lb * JPB;              // LSTM col base
    const int v0  = lb * VPB;              // joint col base (lb<16)
    const int bb0 = grp * GBAT;            // global batch base

    float* H0C2g = ws + H0C2_OFF + grp*2560;
    float* H1C2g = ws + H1C2_OFF + grp*2560;
    float* PL2g  = ws + PL2_OFF  + grp*8192;
    const float* WE = ws + WE_OFF;
    const float* FP = ws + FPRE_OFF;
    int* wi = (int*)ws;
    int* tagD = wi + INT_OFF + grp*320;

    // ---- LDS ----
    __shared__ __align__(16) float wi1_s[64*HPAD];   // 83 KB Wi1 slice (64 gate-rows)
    __shared__ __align__(16) float hs0[GBAT*HPAD];   // h0 candidates
    __shared__ __align__(16) float hs1[GBAT*HPAD];   // h1 candidates
    __shared__ float parts[2048];
    __shared__ float parts2[2048];                   // P0b scratch
    __shared__ float P0a[256], P0b[256], P1s[256];   // 64 gate-rows x 4 batches
    __shared__ float c0cur[64], c0cand[64], c1cur[64], c1cand[64];
    __shared__ float we_s[28][64];
    __shared__ float b0_s[64], b1_s[64], bj2_s[32];
    __shared__ float wj2t[VPB*33];                   // [v][l] transposed
    __shared__ float jg_c[VPB*GBAT];                 // [v][g2]
    __shared__ float hid_s[GBAT*33];
    __shared__ float logits_s[GBAT*33];
    __shared__ int ti_l[GBAT], last_l[GBAT], sa_l[GBAT], lc_l[GBAT], olen_s[GBAT];
    __shared__ unsigned s_masks[2];

    // ---- one-time preload ----
    for (int i = tid; i < 64*PRED_; i += BDEC) {
        int r = i / PRED_, c = i % PRED_;
        int g = r >> 4, jj = r & 15;
        wi1_s[r*HPAD + c] = Wi1[((size_t)(g*PRED_ + j0 + jj))*PRED_ + c];
    }
    if (lb < NJB) {
        for (int i = tid; i < VPB*32; i += BDEC) {
            int v = i >> 5, l = i & 31;
            wj2t[v*33 + l] = (l < VOCAB_) ? Wj2[(size_t)l*JH_ + v0 + v] : 0.f;
        }
    }
    for (int i = tid; i < 28*64; i += BDEC) {
        int ls = i >> 6, r = i & 63;
        int g = r >> 4, jj = r & 15;
        we_s[ls][r] = WE[(size_t)ls*(4*PRED_) + g*PRED_ + j0 + jj];
    }
    if (tid < 64) {
        int g = tid >> 4, jj = tid & 15;
        b0_s[tid] = b0[g*PRED_ + j0 + jj];
        b1_s[tid] = b1[g*PRED_ + j0 + jj];
        c0cur[tid]=0.f; c0cand[tid]=0.f; c1cur[tid]=0.f; c1cand[tid]=0.f;
    }
    if (tid < VOCAB_) bj2_s[tid] = bj2[tid];
    if (tid < GBAT) {
        olen_s[tid] = out_lens[bb0 + tid];
        ti_l[tid] = 0; last_l[tid] = -1; sa_l[tid] = 0; lc_l[tid] = 0;
    }
    for (int i = tid; i < GBAT*HPAD; i += BDEC) { hs0[i] = 0.f; hs1[i] = 0.f; }
    if (tid < 256) P0a[tid] = 0.f;
    __syncthreads();

    const int gb  = tid & 3;          // batch
    const int jl  = (tid >> 2) & 15;  // col within block
    const int ks  = tid >> 6;         // 0..7 (k-chunks of 40)
    unsigned nbm = 0xfu, actm = 0xfu;

    for (int s = 0; s < NSTEPS_; ++s) {
        const int par = s & 1;
        const int st = s + 1;

        // ===== Fpre prefetch (joint blocks; ti known from prev decide) =====
        float f_reg = 0.f;
        if (lb < NJB && tid < 128) {
            int v_ = tid & 31, g2_ = tid >> 5;
            if ((actm >> g2_) & 1) {
                int tm = min(ti_l[g2_], T_ - 1);
                f_reg = FP[((size_t)(bb0+g2_)*T_ + tm)*JH_ + v0 + v_];
            }
        }

        if (nbm) {
            // ===== S1 finalize (pure LDS) + stamped publish h0cand (self via LDS) =====
            if (tid < 64) {
                int g2 = tid & 3, jj = tid >> 2;
                if ((nbm >> g2) & 1) {
                    int ls = last_l[g2];
                    float gt[4];
                    #pragma unroll
                    for (int g = 0; g < 4; ++g) {
                        int r = g*16 + jj;
                        float v = P0a[r*4 + g2] + b0_s[r];
                        if (ls >= 0) v += we_s[ls][r];
                        gt[g] = v;
                    }
                    float cn = sigm(gt[1])*c0cur[tid] + sigm(gt[0])*tanhf(gt[2]);
                    float hn = sigm(gt[3])*tanhf(cn);
                    c0cand[tid] = cn;
                    hs0[g2*HPAD + j0 + jj] = hn;                 // self short-circuit
                    st_pair(&H0C2g[(lb*64 + tid)*2], hn, st);    // publisher-major
                }
            }
            // ===== P1 = Wh1 · h1cur (streamed; covers h0 publish flight -> hopA) =====
            {
                const float* hr = &hs1[gb*HPAD];
                int k0 = ks * 40;
                float a0=0.f,a1=0.f,a2=0.f,a3=0.f;
                const float* w0 = Wh1 + ((size_t)(0*PRED_ + j0 + jl))*PRED_;
                const float* w1 = Wh1 + ((size_t)(1*PRED_ + j0 + jl))*PRED_;
                const float* w2 = Wh1 + ((size_t)(2*PRED_ + j0 + jl))*PRED_;
                const float* w3 = Wh1 + ((size_t)(3*PRED_ + j0 + jl))*PRED_;
                #pragma unroll 10
                for (int kk = k0; kk < k0 + 40; kk += 4) {
                    float4 h = *(const float4*)&hr[kk];
                    float4 q0 = *(const float4*)(w0 + kk);
                    float4 q1 = *(const float4*)(w1 + kk);
                    float4 q2 = *(const float4*)(w2 + kk);
                    float4 q3 = *(const float4*)(w3 + kk);
                    a0 += q0.x*h.x+q0.y*h.y+q0.z*h.z+q0.w*h.w;
                    a1 += q1.x*h.x+q1.y*h.y+q1.z*h.z+q1.w*h.w;
                    a2 += q2.x*h.x+q2.y*h.y+q2.z*h.z+q2.w*h.w;
                    a3 += q3.x*h.x+q3.y*h.y+q3.z*h.z+q3.w*h.w;
                }
                parts[PIDX(0,ks,jl,gb)] = a0;
                parts[PIDX(1,ks,jl,gb)] = a1;
                parts[PIDX(2,ks,jl,gb)] = a2;
                parts[PIDX(3,ks,jl,gb)] = a3;
            }
            __syncthreads();
            // ===== slot-A: hopA gather (tid<320) || P1s reduce (tid>=320) =====
            if (tid >= 320) {
                for (int t = tid - 320; t < 256; t += 192) {
                    int r = t >> 2, g2 = t & 3;
                    int g = r >> 4, jj = r & 15;
                    float v = 0.f;
                    #pragma unroll
                    for (int k = 0; k < 8; ++k) v += parts[PIDX(g,k,jj,g2)];
                    P1s[r*4 + g2] = v;
                }
            } else if ((tid >> 4) != lb) {
                int b = tid >> 4, jj = tid & 15;
                const bool n0=(nbm>>0)&1, n1=(nbm>>1)&1, n2=(nbm>>2)&1, n3=(nbm>>3)&1;
                const float* a0 = H0C2g + tid*8;
                const float* a1 = a0 + 4;
                float4 r0, r1;
                for (;;) {
                    ldc4_2(a0, a1, r0, r1);
                    bool ok = (!n0 || __float_as_int(r0.y)==st)
                           && (!n1 || __float_as_int(r0.w)==st)
                           && (!n2 || __float_as_int(r1.y)==st)
                           && (!n3 || __float_as_int(r1.w)==st);
                    if (ok) break;
                    __builtin_amdgcn_s_sleep(1);
                }
                if (n0) hs0[0*HPAD + b*16 + jj] = r0.x;
                if (n1) hs0[1*HPAD + b*16 + jj] = r0.z;
                if (n2) hs0[2*HPAD + b*16 + jj] = r1.x;
                if (n3) hs0[3*HPAD + b*16 + jj] = r1.z;
            }
            __syncthreads();

            // ===== S2: Wi1·h0cand (LDS weights) =====
            {
                const float* hr = &hs0[gb*HPAD];
                int k0 = ks * 40;
                float a0=0.f,a1=0.f,a2=0.f,a3=0.f;
                #pragma unroll 10
                for (int kk = k0; kk < k0 + 40; kk += 4) {
                    float4 h = *(const float4*)&hr[kk];
                    float4 q0 = *(const float4*)&wi1_s[(0*16+jl)*HPAD + kk];
                    float4 q1 = *(const float4*)&wi1_s[(1*16+jl)*HPAD + kk];
                    float4 q2 = *(const float4*)&wi1_s[(2*16+jl)*HPAD + kk];
                    float4 q3 = *(const float4*)&wi1_s[(3*16+jl)*HPAD + kk];
                    a0 += q0.x*h.x+q0.y*h.y+q0.z*h.z+q0.w*h.w;
                    a1 += q1.x*h.x+q1.y*h.y+q1.z*h.z+q1.w*h.w;
                    a2 += q2.x*h.x+q2.y*h.y+q2.z*h.z+q2.w*h.w;
                    a3 += q3.x*h.x+q3.y*h.y+q3.z*h.z+q3.w*h.w;
                }
                parts[PIDX(0,ks,jl,gb)] = a0;
                parts[PIDX(1,ks,jl,gb)] = a1;
                parts[PIDX(2,ks,jl,gb)] = a2;
                parts[PIDX(3,ks,jl,gb)] = a3;
            }
            __syncthreads();
            // gates1 assemble + stamped publish h1cand (self via LDS)
            if (tid < 64) {
                int g2 = tid & 3, jj = tid >> 2;
                if ((nbm >> g2) & 1) {
                    float gt[4];
                    #pragma unroll
                    for (int g = 0; g < 4; ++g) {
                        int r = g*16 + jj;
                        float v = P1s[r*4 + g2] + b1_s[r];
                        #pragma unroll
                        for (int k = 0; k < 8; ++k) v += parts[PIDX(g,k,jj,g2)];
                        gt[g] = v;
                    }
                    float cn = sigm(gt[1])*c1cur[tid] + sigm(gt[0])*tanhf(gt[2]);
                    float hn = sigm(gt[3])*tanhf(cn);
                    c1cand[tid] = cn;
                    hs1[g2*HPAD + j0 + jj] = hn;                 // self short-circuit
                    st_pair(&H1C2g[(lb*64 + tid)*2], hn, st);
                }
            }
            // ===== P0b gates 0-1 = Wh0 · h0cand (half; covers h1 publish flight -> hopB) =====
            {
                const float* hr = &hs0[gb*HPAD];
                int k0 = ks * 40;
                float a0=0.f,a1=0.f;
                const float* w0 = Wh0 + ((size_t)(0*PRED_ + j0 + jl))*PRED_;
                const float* w1 = Wh0 + ((size_t)(1*PRED_ + j0 + jl))*PRED_;
                #pragma unroll 10
                for (int kk = k0; kk < k0 + 40; kk += 4) {
                    float4 h = *(const float4*)&hr[kk];
                    float4 q0 = *(const float4*)(w0 + kk);
                    float4 q1 = *(const float4*)(w1 + kk);
                    a0 += q0.x*h.x+q0.y*h.y+q0.z*h.z+q0.w*h.w;
                    a1 += q1.x*h.x+q1.y*h.y+q1.z*h.z+q1.w*h.w;
                }
                parts2[PIDX(0,ks,jl,gb)] = a0;
                parts2[PIDX(1,ks,jl,gb)] = a1;
            }
            // ===== hopB: single-RT stamped gather of h1cand =====
            {
                int b = tid >> 4, jj = tid & 15;
                if (tid < 320 && b != lb) {
                    const bool n0=(nbm>>0)&1, n1=(nbm>>1)&1, n2=(nbm>>2)&1, n3=(nbm>>3)&1;
                    const float* a0 = H1C2g + tid*8;
                    const float* a1 = a0 + 4;
                    float4 r0, r1;
                    for (;;) {
                        ldc4_2(a0, a1, r0, r1);
                        bool ok = (!n0 || __float_as_int(r0.y)==st)
                               && (!n1 || __float_as_int(r0.w)==st)
                               && (!n2 || __float_as_int(r1.y)==st)
                               && (!n3 || __float_as_int(r1.w)==st);
                        if (ok) break;
                        __builtin_amdgcn_s_sleep(1);
                    }
                    if (n0) hs1[0*HPAD + b*16 + jj] = r0.x;
                    if (n1) hs1[1*HPAD + b*16 + jj] = r0.z;
                    if (n2) hs1[2*HPAD + b*16 + jj] = r1.x;
                    if (n3) hs1[3*HPAD + b*16 + jj] = r1.z;
                }
            }
            __syncthreads();
        } else {
            // blank step: PL[par] overwrite needs step-(s-2) readers done
            if (lb < NJB) {
                if (tid < NBLK) { while (ld_i(&tagD[tid*16]) < s-1) __builtin_amdgcn_s_sleep(1); }
                __syncthreads();
            }
        }

        // ===== S3a: joint blocks =====
        if (lb < NJB) {
            if (nbm) {
                int v = tid & 31, g2 = (tid >> 5) & 3, ks2 = tid >> 7;
                if ((nbm >> g2) & 1) {
                    const float* hr = &hs1[g2*HPAD];
                    const float* wt = Wj1 + ((size_t)(v0 + v))*NJ_ + ENC_ + ks2*80;
                    const float* hk = hr + ks2*80;
                    float p = 0.f;
                    #pragma unroll 20
                    for (int kk = 0; kk < 80; kk += 4) {
                        float4 w4 = *(const float4*)(wt + kk);
                        float4 h  = *(const float4*)(hk + kk);
                        p += w4.x*h.x + w4.y*h.y + w4.z*h.z + w4.w*h.w;
                    }
                    parts[(v*4 + g2)*4 + ks2] = p;
                }
            }
            __syncthreads();
            if (tid < 128) {
                int v = tid & 31, g2 = tid >> 5;
                if (nbm && ((nbm >> g2) & 1)) {
                    jg_c[v*4 + g2] = parts[(v*4+g2)*4+0] + parts[(v*4+g2)*4+1]
                                   + parts[(v*4+g2)*4+2] + parts[(v*4+g2)*4+3];
                }
                if ((actm >> g2) & 1) {
                    hid_s[g2*33 + v] = fmaxf(f_reg + jg_c[v*4 + g2], 0.f);
                }
            }
            __syncthreads();
            if (tid < 128) {
                int g2 = tid >> 5, l = tid & 31;
                const float* hb = &hid_s[g2*33];
                float acc = 0.f;
                #pragma unroll 8
                for (int v = 0; v < VPB; ++v) acc += wj2t[v*33 + l] * hb[v];
                st_pair(&PL2g[par*4096 + (lb*128 + tid)*2], acc, st);
            }
        }

        // ===== P0b gates 2-3 (half; covers PL publish flight -> hopC) =====
        if (nbm) {
            const float* hr = &hs0[gb*HPAD];
            int k0 = ks * 40;
            float a2=0.f,a3=0.f;
            const float* w2 = Wh0 + ((size_t)(2*PRED_ + j0 + jl))*PRED_;
            const float* w3 = Wh0 + ((size_t)(3*PRED_ + j0 + jl))*PRED_;
            #pragma unroll 10
            for (int kk = k0; kk < k0 + 40; kk += 4) {
                float4 h = *(const float4*)&hr[kk];
                float4 q2 = *(const float4*)(w2 + kk);
                float4 q3 = *(const float4*)(w3 + kk);
                a2 += q2.x*h.x+q2.y*h.y+q2.z*h.z+q2.w*h.w;
                a3 += q3.x*h.x+q3.y*h.y+q3.z*h.z+q3.w*h.w;
            }
            parts2[PIDX(2,ks,jl,gb)] = a2;
            parts2[PIDX(3,ks,jl,gb)] = a3;
        }

        // ===== hopC: publisher-isolated stamped gather (thread -> ONE jb, 32B) =====
        {
            int p0 = tid * 4;                              // pairs p0..p0+3, jb = tid>>5
            const float* a0 = PL2g + par*4096 + p0*2;
            float4 r0, r1;
            for (;;) {
                ldc4_2(a0, a0 + 4, r0, r1);
                if (__float_as_int(r0.y)==st && __float_as_int(r0.w)==st &&
                    __float_as_int(r1.y)==st && __float_as_int(r1.w)==st) break;
                __builtin_amdgcn_s_sleep(1);
            }
            parts[p0+0]=r0.x; parts[p0+1]=r0.z; parts[p0+2]=r1.x; parts[p0+3]=r1.z;
        }
        __syncthreads();
        // ===== logits assembly (tid<128) || P0b reduce (tid>=256) =====
        if (tid < 128) {
            float v = 0.f;
            #pragma unroll
            for (int jb = 0; jb < 16; ++jb) v += parts[jb*128 + tid];
            int g2 = tid >> 5, l = tid & 31;
            logits_s[g2*33 + l] = (l < VOCAB_) ? (v + bj2_s[l]) : -1e30f;
        } else if (tid >= 256 && nbm) {
            int t = tid - 256;
            int r = t >> 2, g2 = t & 3;
            int g = r >> 4, jj = r & 15;
            float v = 0.f;
            #pragma unroll
            for (int k = 0; k < 8; ++k) v += parts2[PIDX(g,k,jj,g2)];
            P0b[r*4 + g2] = v;
        }
        __syncthreads();

        // ===== local redundant decide (one wave + ballot) =====
        if (tid < 64) {
            bool nbb = false, actb = false;
            if (tid < GBAT && ((actm >> tid) & 1)) {
                const int g2 = tid;
                float best = -1e30f; int bi = 0;
                for (int l = 0; l < VOCAB_; ++l) {
                    float v = logits_s[g2*33 + l];
                    if (v > best) { best = v; bi = l; }
                }
                const int blankness = (bi == BLANK_) ? 1 : 0;
                int tiv = ti_l[g2] + blankness;
                if (tiv >= olen_s[g2]) {
                    ti_l[g2] = tiv;                      // frozen
                } else {
                    int notb = 1 - blankness;
                    int sav = blankness ? 0 : sa_l[g2];
                    int nl = last_l[g2];
                    int lcn = lc_l[g2];
                    if (notb) {
                        lcn += 1;
                        if (lb == g2) {                  // designated writer
                            int bglob = bb0 + g2;
                            if (lcn < NSTEPS_) st_i(&out[bglob*NSTEPS_ + lcn], bi);
                            st_i(&out[B_*NSTEPS_ + bglob], lcn);
                        }
                        nl = bi;
                        sav += 1;
                    }
                    if (sav >= MAXSYM_) { tiv += 1; sav = 0; }
                    ti_l[g2] = tiv; sa_l[g2] = sav; last_l[g2] = nl; lc_l[g2] = lcn;
                    nbb = (notb != 0); actb = true;
                }
            }
            unsigned long long bn = __ballot(nbb);
            unsigned long long ba = __ballot(actb);
            if (tid == 0) { s_masks[0] = (unsigned)bn; s_masks[1] = (unsigned)ba; }
        }
        __syncthreads();
        const unsigned nbm_new = s_masks[0];
        actm = s_masks[1];
        // commit accepted candidates + speculative P0
        if (tid < 64) {
            if ((nbm_new >> (tid & 3)) & 1) { c0cur[tid] = c0cand[tid]; c1cur[tid] = c1cand[tid]; }
        }
        if (tid < 256) {
            if ((nbm_new >> (tid & 3)) & 1) P0a[tid] = P0b[tid];
        }
        __syncthreads();
        nbm = nbm_new;
        if (tid == 0) st_i(&tagD[lb*16], s + 1);
        if (!actm) break;
    }
}

extern "C" void kernel_launch(void* const* d_in, const int* in_sizes, int n_in,
                              void* d_out, int out_size, void* d_ws, size_t ws_size,
                              hipStream_t stream) {
    const float* x    = (const float*)d_in[0];
    const int*   olen = (const int*)d_in[1];
    const float* emb  = (const float*)d_in[2];
    const float* Wi0  = (const float*)d_in[3];
    const float* Wh0  = (const float*)d_in[4];
    const float* b0   = (const float*)d_in[5];
    const float* Wi1  = (const float*)d_in[6];
    const float* Wh1  = (const float*)d_in[7];
    const float* b1   = (const float*)d_in[8];
    const float* Wj1  = (const float*)d_in[9];
    const float* bj1  = (const float*)d_in[10];
    const float* Wj2  = (const float*)d_in[11];
    const float* bj2  = (const float*)d_in[12];
    float* ws = (float*)d_ws;
    int* out = (int*)d_out;

    hipLaunchKernelGGL(k_init, dim3(256), dim3(256), 0, stream, ws, out);
    hipLaunchKernelGGL(k_we,   dim3(28*5), dim3(256), 0, stream, emb, Wi0, ws);
    hipLaunchKernelGGL(k_fpre, dim3(T_*8), dim3(256), 0, stream, x, Wj1, bj1, ws);
    hipLaunchKernelGGL(k_decode, dim3(GRID_DEC), dim3(BDEC), 0, stream,
                       olen, Wh0, b0, Wi1, Wh1, b1, Wj1, Wj2, bj2, ws, out);
}

// Round 11
// 4099.158 us; speedup vs baseline: 1.3189x; 1.0098x over previous
//
#include <hip/hip_runtime.h>
#include <math.h>

#define B_ 32
#define T_ 48
#define ENC_ 1024
#define PRED_ 320
#define JH_ 512
#define NJ_ 1344
#define VOCAB_ 29
#define BLANK_ 28
#define MAXSYM_ 6
#define NSTEPS_ 288
#define BDEC 512
#define GRID_DEC 160
#define NG 8        // independent groups
#define GBAT 4      // batches per group
#define NBLK 20     // blocks per group
#define JPB 16      // LSTM h-cols per block (320/20)
#define NJB 16      // joint blocks per group
#define VPB 32      // joint v-cols per joint block
#define HPAD 324    // padded h row

// ---- workspace layout (float indices) ----
// Stamped (value,step) 8B pairs, publisher-major.
#define FPRE_OFF 0                // 786432
#define WE_OFF   786432           // 28*1280 = 35840
#define H0C2_OFF 822272           // + grp*2560 : 20 blk x 64 pairs (publisher-major)
#define H1C2_OFF 842752           // + grp*2560
#define PL2_OFF  863232           // + grp*8192 + par*4096 : 16 blk x 128 pairs
#define INT_OFF  928768           // tagD only: grp*320 + lb*16
#define NTAGS    2560
#define STAMPF   106496           // floats to zero from H0C2_OFF

__device__ __forceinline__ float sigm(float v) { return 1.0f / (1.0f + expf(-v)); }

__device__ __forceinline__ int  ld_i(const int* p)   { return __hip_atomic_load((int*)p, __ATOMIC_RELAXED, __HIP_MEMORY_SCOPE_AGENT); }
__device__ __forceinline__ void st_i(int* p, int v)  { __hip_atomic_store(p, v, __ATOMIC_RELAXED, __HIP_MEMORY_SCOPE_AGENT); }

// single-instruction 8B publish: (value, stamp) — self-validating, MALL-visible
__device__ __forceinline__ void st_pair(float* p, float v, int stamp) {
    float2 x; x.x = v; x.y = __int_as_float(stamp);
    asm volatile("global_store_dwordx2 %0, %1, off sc0 sc1" :: "v"(p), "v"(x) : "memory");
}
// fused coherent loads (MALL-served), wait folded in
__device__ __forceinline__ void ldc4_2(const float* p0, const float* p1,
                                       float4& r0, float4& r1) {
    asm volatile("global_load_dwordx4 %0, %2, off sc0 sc1\n\t"
                 "global_load_dwordx4 %1, %3, off sc0 sc1\n\t"
                 "s_waitcnt vmcnt(0)"
                 : "=&v"(r0), "=&v"(r1)
                 : "v"(p0), "v"(p1)
                 : "memory");
}

#define PIDX(g, ks, jl, gb) ((((g)*8 + (ks))*16 + (jl))*4 + (gb))

// ---------------- init ----------------
__global__ void k_init(float* __restrict__ ws, int* __restrict__ out) {
    int idx = blockIdx.x * blockDim.x + threadIdx.x;
    int stride = gridDim.x * blockDim.x;
    for (int i = idx; i < STAMPF; i += stride) ws[H0C2_OFF + i] = 0.0f;  // stamps=0
    int* wi = (int*)ws;
    for (int i = idx; i < NTAGS; i += stride) wi[INT_OFF + i] = 0;
    for (int i = idx; i < B_*NSTEPS_; i += stride) out[i] = -1;  // lt
    if (idx < B_) out[B_*NSTEPS_ + idx] = 0;                     // lc
}

// ---------------- WE = emb @ Wi0^T  (28 x 1280) ----------------
__global__ __launch_bounds__(256) void k_we(const float* __restrict__ emb,
                                            const float* __restrict__ Wi0,
                                            float* __restrict__ ws) {
    __shared__ float es[PRED_];
    int l = blockIdx.x / 5;
    int rq = blockIdx.x % 5;
    int t = threadIdx.x;
    if (t < PRED_) es[t] = emb[l*PRED_ + t];
    if (t + 256 < PRED_) es[t + 256] = emb[l*PRED_ + t + 256];
    __syncthreads();
    int r = rq*256 + t;
    const float4* wr = (const float4*)(Wi0 + (size_t)r*PRED_);
    float acc = 0.0f;
    #pragma unroll 4
    for (int k4 = 0; k4 < PRED_/4; ++k4) {
        float4 w = wr[k4];
        acc += w.x*es[4*k4] + w.y*es[4*k4+1] + w.z*es[4*k4+2] + w.w*es[4*k4+3];
    }
    ws[WE_OFF + l*(4*PRED_) + r] = acc;
}

// ---------------- Fpre[b][t][j] = x[b,t]·Wj1[j,:1024] + bj1[j] ----------------
__global__ __launch_bounds__(256) void k_fpre(const float* __restrict__ x,
                                              const float* __restrict__ Wj1,
                                              const float* __restrict__ bj1,
                                              float* __restrict__ ws) {
    __shared__ float As[B_][129];
    __shared__ float Bs[64][129];
    int tt = blockIdx.x >> 3;
    int jb = blockIdx.x & 7;
    int tid = threadIdx.x;
    int b = tid >> 3, jq = tid & 7;
    float acc[8] = {0,0,0,0,0,0,0,0};
    for (int kc = 0; kc < ENC_; kc += 128) {
        for (int i = tid; i < B_*128; i += 256) {
            int bb = i >> 7, kk = i & 127;
            As[bb][kk] = x[((size_t)bb*T_ + tt)*ENC_ + kc + kk];
        }
        for (int i = tid; i < 64*128; i += 256) {
            int jj = i >> 7, kk = i & 127;
            Bs[jj][kk] = Wj1[((size_t)(jb*64 + jj))*NJ_ + kc + kk];
        }
        __syncthreads();
        for (int kk = 0; kk < 128; ++kk) {
            float a = As[b][kk];
            #pragma unroll
            for (int u = 0; u < 8; ++u) acc[u] += a * Bs[jq*8 + u][kk];
        }
        __syncthreads();
    }
    #pragma unroll
    for (int u = 0; u < 8; ++u) {
        int j = jb*64 + jq*8 + u;
        ws[FPRE_OFF + ((size_t)b*T_ + tt)*JH_ + j] = acc[u] + bj1[j];
    }
}

// ---------------- persistent decode: 8 independent groups of 20 blocks ----------------
__global__ __launch_bounds__(BDEC) void k_decode(
    const int* __restrict__ out_lens,
    const float* __restrict__ Wh0, const float* __restrict__ b0,
    const float* __restrict__ Wi1, const float* __restrict__ Wh1,
    const float* __restrict__ b1,
    const float* __restrict__ Wj1,
    const float* __restrict__ Wj2, const float* __restrict__ bj2,
    float* __restrict__ ws, int* __restrict__ out)
{
    const int tid = threadIdx.x;
    const int grp = blockIdx.x & 7;        // group
    const int lb  = blockIdx.x >> 3;       // 0..19 group-local
    const int j0  = lb * JPB;              // LSTM col base
    const int v0  = lb * VPB;              // joint col base (lb<16)
    const int bb0 = grp * GBAT;            // global batch base

    float* H0C2g = ws + H0C2_OFF + grp*2560;
    float* H1C2g = ws + H1C2_OFF + grp*2560;
    float* PL2g  = ws + PL2_OFF  + grp*8192;
    const float* WE = ws + WE_OFF;
    const float* FP = ws + FPRE_OFF;
    int* wi = (int*)ws;
    int* tagD = wi + INT_OFF + grp*320;

    // ---- LDS ----
    __shared__ __align__(16) float wi1_s[64*HPAD];   // 83 KB Wi1 slice (64 gate-rows)
    __shared__ __align__(16) float hs0[GBAT*HPAD];   // h0 candidates
    __shared__ __align__(16) float hs1[GBAT*HPAD];   // h1 candidates
    __shared__ float parts[2048];
    __shared__ float parts2[2048];                   // P0b scratch
    __shared__ float P0b[256], P1s[256];             // speculative P0 / P1 (no commit copy)
    __shared__ float c0cand[64], c1cand[64];         // pending==committed for nbm batches
    __shared__ float we_s[28][64];
    __shared__ float b0_s[64], b1_s[64], bj2_s[32];
    __shared__ float wj2t[VPB*33];                   // [v][l] transposed
    __shared__ float jg_c[VPB*GBAT];                 // [v][g2]
    __shared__ float hid_s[GBAT*33];
    __shared__ float logits_s[GBAT*33];
    __shared__ int ti_l[GBAT], last_l[GBAT], sa_l[GBAT], lc_l[GBAT], olen_s[GBAT];
    __shared__ unsigned s_masks[2];

    // ---- one-time preload ----
    for (int i = tid; i < 64*PRED_; i += BDEC) {
        int r = i / PRED_, c = i % PRED_;
        int g = r >> 4, jj = r & 15;
        wi1_s[r*HPAD + c] = Wi1[((size_t)(g*PRED_ + j0 + jj))*PRED_ + c];
    }
    if (lb < NJB) {
        for (int i = tid; i < VPB*32; i += BDEC) {
            int v = i >> 5, l = i & 31;
            wj2t[v*33 + l] = (l < VOCAB_) ? Wj2[(size_t)l*JH_ + v0 + v] : 0.f;
        }
    }
    for (int i = tid; i < 28*64; i += BDEC) {
        int ls = i >> 6, r = i & 63;
        int g = r >> 4, jj = r & 15;
        we_s[ls][r] = WE[(size_t)ls*(4*PRED_) + g*PRED_ + j0 + jj];
    }
    if (tid < 64) {
        int g = tid >> 4, jj = tid & 15;
        b0_s[tid] = b0[g*PRED_ + j0 + jj];
        b1_s[tid] = b1[g*PRED_ + j0 + jj];
        c0cand[tid] = 0.f; c1cand[tid] = 0.f;
    }
    if (tid < VOCAB_) bj2_s[tid] = bj2[tid];
    if (tid < GBAT) {
        olen_s[tid] = out_lens[bb0 + tid];
        ti_l[tid] = 0; last_l[tid] = -1; sa_l[tid] = 0; lc_l[tid] = 0;
    }
    for (int i = tid; i < GBAT*HPAD; i += BDEC) { hs0[i] = 0.f; hs1[i] = 0.f; }
    if (tid < 256) P0b[tid] = 0.f;
    __syncthreads();

    const int gb  = tid & 3;          // batch
    const int jl  = (tid >> 2) & 15;  // col within block
    const int ks  = tid >> 6;         // 0..7 (k-chunks of 40)
    unsigned nbm = 0xfu, actm = 0xfu;

    for (int s = 0; s < NSTEPS_; ++s) {
        const int par = s & 1;
        const int st = s + 1;

        // ===== Fpre prefetch (joint blocks; ti known from prev decide) =====
        float f_reg = 0.f;
        if (lb < NJB && tid < 128) {
            int v_ = tid & 31, g2_ = tid >> 5;
            if ((actm >> g2_) & 1) {
                int tm = min(ti_l[g2_], T_ - 1);
                f_reg = FP[((size_t)(bb0+g2_)*T_ + tm)*JH_ + v0 + v_];
            }
        }

        if (nbm) {
            // ===== S1 finalize (pure LDS; reads pending==committed state) + publish =====
            if (tid < 64) {
                int g2 = tid & 3, jj = tid >> 2;
                if ((nbm >> g2) & 1) {
                    int ls = last_l[g2];
                    float gt[4];
                    #pragma unroll
                    for (int g = 0; g < 4; ++g) {
                        int r = g*16 + jj;
                        float v = P0b[r*4 + g2] + b0_s[r];
                        if (ls >= 0) v += we_s[ls][r];
                        gt[g] = v;
                    }
                    float cn = sigm(gt[1])*c0cand[tid] + sigm(gt[0])*tanhf(gt[2]);
                    float hn = sigm(gt[3])*tanhf(cn);
                    c0cand[tid] = cn;
                    hs0[g2*HPAD + j0 + jj] = hn;                 // self short-circuit
                    st_pair(&H0C2g[(lb*64 + tid)*2], hn, st);    // publisher-major
                }
            }
            // ===== P1 = Wh1 · h1cur (streamed; covers h0 publish flight -> hopA) =====
            {
                const float* hr = &hs1[gb*HPAD];
                int k0 = ks * 40;
                float a0=0.f,a1=0.f,a2=0.f,a3=0.f;
                const float* w0 = Wh1 + ((size_t)(0*PRED_ + j0 + jl))*PRED_;
                const float* w1 = Wh1 + ((size_t)(1*PRED_ + j0 + jl))*PRED_;
                const float* w2 = Wh1 + ((size_t)(2*PRED_ + j0 + jl))*PRED_;
                const float* w3 = Wh1 + ((size_t)(3*PRED_ + j0 + jl))*PRED_;
                #pragma unroll 10
                for (int kk = k0; kk < k0 + 40; kk += 4) {
                    float4 h = *(const float4*)&hr[kk];
                    float4 q0 = *(const float4*)(w0 + kk);
                    float4 q1 = *(const float4*)(w1 + kk);
                    float4 q2 = *(const float4*)(w2 + kk);
                    float4 q3 = *(const float4*)(w3 + kk);
                    a0 += q0.x*h.x+q0.y*h.y+q0.z*h.z+q0.w*h.w;
                    a1 += q1.x*h.x+q1.y*h.y+q1.z*h.z+q1.w*h.w;
                    a2 += q2.x*h.x+q2.y*h.y+q2.z*h.z+q2.w*h.w;
                    a3 += q3.x*h.x+q3.y*h.y+q3.z*h.z+q3.w*h.w;
                }
                parts[PIDX(0,ks,jl,gb)] = a0;
                parts[PIDX(1,ks,jl,gb)] = a1;
                parts[PIDX(2,ks,jl,gb)] = a2;
                parts[PIDX(3,ks,jl,gb)] = a3;
            }
            __syncthreads();
            // ===== slot-A: hopA gather (tid<320) || P1s reduce (tid>=320) =====
            if (tid >= 320) {
                for (int t = tid - 320; t < 256; t += 192) {
                    int r = t >> 2, g2 = t & 3;
                    int g = r >> 4, jj = r & 15;
                    float v = 0.f;
                    #pragma unroll
                    for (int k = 0; k < 8; ++k) v += parts[PIDX(g,k,jj,g2)];
                    P1s[r*4 + g2] = v;
                }
            } else if ((tid >> 4) != lb) {
                int b = tid >> 4, jj = tid & 15;
                const bool n0=(nbm>>0)&1, n1=(nbm>>1)&1, n2=(nbm>>2)&1, n3=(nbm>>3)&1;
                const float* a0 = H0C2g + tid*8;
                const float* a1 = a0 + 4;
                float4 r0, r1;
                for (;;) {
                    ldc4_2(a0, a1, r0, r1);
                    bool ok = (!n0 || __float_as_int(r0.y)==st)
                           && (!n1 || __float_as_int(r0.w)==st)
                           && (!n2 || __float_as_int(r1.y)==st)
                           && (!n3 || __float_as_int(r1.w)==st);
                    if (ok) break;
                    __builtin_amdgcn_s_sleep(1);
                }
                if (n0) hs0[0*HPAD + b*16 + jj] = r0.x;
                if (n1) hs0[1*HPAD + b*16 + jj] = r0.z;
                if (n2) hs0[2*HPAD + b*16 + jj] = r1.x;
                if (n3) hs0[3*HPAD + b*16 + jj] = r1.z;
            }
            __syncthreads();

            // ===== S2: Wi1·h0cand (LDS weights) =====
            {
                const float* hr = &hs0[gb*HPAD];
                int k0 = ks * 40;
                float a0=0.f,a1=0.f,a2=0.f,a3=0.f;
                #pragma unroll 10
                for (int kk = k0; kk < k0 + 40; kk += 4) {
                    float4 h = *(const float4*)&hr[kk];
                    float4 q0 = *(const float4*)&wi1_s[(0*16+jl)*HPAD + kk];
                    float4 q1 = *(const float4*)&wi1_s[(1*16+jl)*HPAD + kk];
                    float4 q2 = *(const float4*)&wi1_s[(2*16+jl)*HPAD + kk];
                    float4 q3 = *(const float4*)&wi1_s[(3*16+jl)*HPAD + kk];
                    a0 += q0.x*h.x+q0.y*h.y+q0.z*h.z+q0.w*h.w;
                    a1 += q1.x*h.x+q1.y*h.y+q1.z*h.z+q1.w*h.w;
                    a2 += q2.x*h.x+q2.y*h.y+q2.z*h.z+q2.w*h.w;
                    a3 += q3.x*h.x+q3.y*h.y+q3.z*h.z+q3.w*h.w;
                }
                parts[PIDX(0,ks,jl,gb)] = a0;
                parts[PIDX(1,ks,jl,gb)] = a1;
                parts[PIDX(2,ks,jl,gb)] = a2;
                parts[PIDX(3,ks,jl,gb)] = a3;
            }
            __syncthreads();
            // gates1 assemble + stamped publish h1cand (self via LDS)
            if (tid < 64) {
                int g2 = tid & 3, jj = tid >> 2;
                if ((nbm >> g2) & 1) {
                    float gt[4];
                    #pragma unroll
                    for (int g = 0; g < 4; ++g) {
                        int r = g*16 + jj;
                        float v = P1s[r*4 + g2] + b1_s[r];
                        #pragma unroll
                        for (int k = 0; k < 8; ++k) v += parts[PIDX(g,k,jj,g2)];
                        gt[g] = v;
                    }
                    float cn = sigm(gt[1])*c1cand[tid] + sigm(gt[0])*tanhf(gt[2]);
                    float hn = sigm(gt[3])*tanhf(cn);
                    c1cand[tid] = cn;
                    hs1[g2*HPAD + j0 + jj] = hn;                 // self short-circuit
                    st_pair(&H1C2g[(lb*64 + tid)*2], hn, st);
                }
            }
            // ===== P0b gates 0-1 = Wh0 · h0cand (half; covers h1 publish flight -> hopB) =====
            {
                const float* hr = &hs0[gb*HPAD];
                int k0 = ks * 40;
                float a0=0.f,a1=0.f;
                const float* w0 = Wh0 + ((size_t)(0*PRED_ + j0 + jl))*PRED_;
                const float* w1 = Wh0 + ((size_t)(1*PRED_ + j0 + jl))*PRED_;
                #pragma unroll 10
                for (int kk = k0; kk < k0 + 40; kk += 4) {
                    float4 h = *(const float4*)&hr[kk];
                    float4 q0 = *(const float4*)(w0 + kk);
                    float4 q1 = *(const float4*)(w1 + kk);
                    a0 += q0.x*h.x+q0.y*h.y+q0.z*h.z+q0.w*h.w;
                    a1 += q1.x*h.x+q1.y*h.y+q1.z*h.z+q1.w*h.w;
                }
                parts2[PIDX(0,ks,jl,gb)] = a0;
                parts2[PIDX(1,ks,jl,gb)] = a1;
            }
            // ===== hopB: single-RT stamped gather of h1cand =====
            {
                int b = tid >> 4, jj = tid & 15;
                if (tid < 320 && b != lb) {
                    const bool n0=(nbm>>0)&1, n1=(nbm>>1)&1, n2=(nbm>>2)&1, n3=(nbm>>3)&1;
                    const float* a0 = H1C2g + tid*8;
                    const float* a1 = a0 + 4;
                    float4 r0, r1;
                    for (;;) {
                        ldc4_2(a0, a1, r0, r1);
                        bool ok = (!n0 || __float_as_int(r0.y)==st)
                               && (!n1 || __float_as_int(r0.w)==st)
                               && (!n2 || __float_as_int(r1.y)==st)
                               && (!n3 || __float_as_int(r1.w)==st);
                        if (ok) break;
                        __builtin_amdgcn_s_sleep(1);
                    }
                    if (n0) hs1[0*HPAD + b*16 + jj] = r0.x;
                    if (n1) hs1[1*HPAD + b*16 + jj] = r0.z;
                    if (n2) hs1[2*HPAD + b*16 + jj] = r1.x;
                    if (n3) hs1[3*HPAD + b*16 + jj] = r1.z;
                }
            }
            __syncthreads();
        } else {
            // blank step: PL[par] overwrite needs step-(s-2) readers done
            if (lb < NJB) {
                if (tid < NBLK) { while (ld_i(&tagD[tid*16]) < s-1) __builtin_amdgcn_s_sleep(1); }
                __syncthreads();
            }
        }

        // ===== S3a: joint blocks =====
        if (lb < NJB) {
            if (nbm) {
                int v = tid & 31, g2 = (tid >> 5) & 3, ks2 = tid >> 7;
                if ((nbm >> g2) & 1) {
                    const float* hr = &hs1[g2*HPAD];
                    const float* wt = Wj1 + ((size_t)(v0 + v))*NJ_ + ENC_ + ks2*80;
                    const float* hk = hr + ks2*80;
                    float p = 0.f;
                    #pragma unroll 20
                    for (int kk = 0; kk < 80; kk += 4) {
                        float4 w4 = *(const float4*)(wt + kk);
                        float4 h  = *(const float4*)(hk + kk);
                        p += w4.x*h.x + w4.y*h.y + w4.z*h.z + w4.w*h.w;
                    }
                    parts[(v*4 + g2)*4 + ks2] = p;
                }
            }
            __syncthreads();
            if (tid < 128) {
                int v = tid & 31, g2 = tid >> 5;
                if (nbm && ((nbm >> g2) & 1)) {
                    jg_c[v*4 + g2] = parts[(v*4+g2)*4+0] + parts[(v*4+g2)*4+1]
                                   + parts[(v*4+g2)*4+2] + parts[(v*4+g2)*4+3];
                }
                if ((actm >> g2) & 1) {
                    hid_s[g2*33 + v] = fmaxf(f_reg + jg_c[v*4 + g2], 0.f);
                }
            }
            __syncthreads();
            if (tid < 128) {
                int g2 = tid >> 5, l = tid & 31;
                const float* hb = &hid_s[g2*33];
                float acc = 0.f;
                #pragma unroll 8
                for (int v = 0; v < VPB; ++v) acc += wj2t[v*33 + l] * hb[v];
                st_pair(&PL2g[par*4096 + (lb*128 + tid)*2], acc, st);
            }
        }

        // ===== P0b gates 2-3 (half; covers PL publish flight -> hopC) =====
        if (nbm) {
            const float* hr = &hs0[gb*HPAD];
            int k0 = ks * 40;
            float a2=0.f,a3=0.f;
            const float* w2 = Wh0 + ((size_t)(2*PRED_ + j0 + jl))*PRED_;
            const float* w3 = Wh0 + ((size_t)(3*PRED_ + j0 + jl))*PRED_;
            #pragma unroll 10
            for (int kk = k0; kk < k0 + 40; kk += 4) {
                float4 h = *(const float4*)&hr[kk];
                float4 q2 = *(const float4*)(w2 + kk);
                float4 q3 = *(const float4*)(w3 + kk);
                a2 += q2.x*h.x+q2.y*h.y+q2.z*h.z+q2.w*h.w;
                a3 += q3.x*h.x+q3.y*h.y+q3.z*h.z+q3.w*h.w;
            }
            parts2[PIDX(2,ks,jl,gb)] = a2;
            parts2[PIDX(3,ks,jl,gb)] = a3;
        }

        // ===== hopC: publisher-isolated stamped gather (thread -> ONE jb, 32B) =====
        {
            int p0 = tid * 4;                              // pairs p0..p0+3, jb = tid>>5
            const float* a0 = PL2g + par*4096 + p0*2;
            float4 r0, r1;
            for (;;) {
                ldc4_2(a0, a0 + 4, r0, r1);
                if (__float_as_int(r0.y)==st && __float_as_int(r0.w)==st &&
                    __float_as_int(r1.y)==st && __float_as_int(r1.w)==st) break;
                __builtin_amdgcn_s_sleep(1);
            }
            parts[p0+0]=r0.x; parts[p0+1]=r0.z; parts[p0+2]=r1.x; parts[p0+3]=r1.z;
        }
        __syncthreads();
        // ===== logits assembly (tid<128) || P0b reduce (tid>=256) =====
        if (tid < 128) {
            float v = 0.f;
            #pragma unroll
            for (int jb = 0; jb < 16; ++jb) v += parts[jb*128 + tid];
            int g2 = tid >> 5, l = tid & 31;
            logits_s[g2*33 + l] = (l < VOCAB_) ? (v + bj2_s[l]) : -1e30f;
        } else if (tid >= 256 && nbm) {
            int t = tid - 256;
            int r = t >> 2, g2 = t & 3;
            int g = r >> 4, jj = r & 15;
            float v = 0.f;
            #pragma unroll
            for (int k = 0; k < 8; ++k) v += parts2[PIDX(g,k,jj,g2)];
            P0b[r*4 + g2] = v;
        }
        __syncthreads();

        // ===== local redundant decide (one wave + ballot); no commit pass =====
        if (tid < 64) {
            bool nbb = false, actb = false;
            if (tid < GBAT && ((actm >> tid) & 1)) {
                const int g2 = tid;
                float best = -1e30f; int bi = 0;
                for (int l = 0; l < VOCAB_; ++l) {
                    float v = logits_s[g2*33 + l];
                    if (v > best) { best = v; bi = l; }
                }
                const int blankness = (bi == BLANK_) ? 1 : 0;
                int tiv = ti_l[g2] + blankness;
                if (tiv >= olen_s[g2]) {
                    ti_l[g2] = tiv;                      // frozen
                } else {
                    int notb = 1 - blankness;
                    int sav = blankness ? 0 : sa_l[g2];
                    int nl = last_l[g2];
                    int lcn = lc_l[g2];
                    if (notb) {
                        lcn += 1;
                        if (lb == g2) {                  // designated writer
                            int bglob = bb0 + g2;
                            if (lcn < NSTEPS_) st_i(&out[bglob*NSTEPS_ + lcn], bi);
                            st_i(&out[B_*NSTEPS_ + bglob], lcn);
                        }
                        nl = bi;
                        sav += 1;
                    }
                    if (sav >= MAXSYM_) { tiv += 1; sav = 0; }
                    ti_l[g2] = tiv; sa_l[g2] = sav; last_l[g2] = nl; lc_l[g2] = lcn;
                    nbb = (notb != 0); actb = true;
                }
            }
            unsigned long long bn = __ballot(nbb);
            unsigned long long ba = __ballot(actb);
            if (tid == 0) { s_masks[0] = (unsigned)bn; s_masks[1] = (unsigned)ba; }
        }
        __syncthreads();
        nbm = s_masks[0];
        actm = s_masks[1];
        if (tid == 0) st_i(&tagD[lb*16], s + 1);
        if (!actm) break;
    }
}

extern "C" void kernel_launch(void* const* d_in, const int* in_sizes, int n_in,
                              void* d_out, int out_size, void* d_ws, size_t ws_size,
                              hipStream_t stream) {
    const float* x    = (const float*)d_in[0];
    const int*   olen = (const int*)d_in[1];
    const float* emb  = (const float*)d_in[2];
    const float* Wi0  = (const float*)d_in[3];
    const float* Wh0  = (const float*)d_in[4];
    const float* b0   = (const float*)d_in[5];
    const float* Wi1  = (const float*)d_in[6];
    const float* Wh1  = (const float*)d_in[7];
    const float* b1   = (const float*)d_in[8];
    const float* Wj1  = (const float*)d_in[9];
    const float* bj1  = (const float*)d_in[10];
    const float* Wj2  = (const float*)d_in[11];
    const float* bj2  = (const float*)d_in[12];
    float* ws = (float*)d_ws;
    int* out = (int*)d_out;

    hipLaunchKernelGGL(k_init, dim3(256), dim3(256), 0, stream, ws, out);
    hipLaunchKernelGGL(k_we,   dim3(28*5), dim3(256), 0, stream, emb, Wi0, ws);
    hipLaunchKernelGGL(k_fpre, dim3(T_*8), dim3(256), 0, stream, x, Wj1, bj1, ws);
    hipLaunchKernelGGL(k_decode, dim3(GRID_DEC), dim3(BDEC), 0, stream,
                       olen, Wh0, b0, Wi1, Wh1, b1, Wj1, Wj2, bj2, ws, out);
}